// Round 1
// baseline (100.022 us; speedup 1.0000x reference)
//
#include <hip/hip_runtime.h>
#include <hip/hip_bf16.h>

#define BCH 32   // B*C heads
#define NN  2048
#define DD  64   // F = H = O

typedef __attribute__((ext_vector_type(8))) __bf16 bf16x8;
typedef __attribute__((ext_vector_type(4))) float f32x4;
typedef __attribute__((ext_vector_type(4))) int   i32x4;

__device__ inline f32x4 mfma_bf16(bf16x8 a, bf16x8 b, f32x4 c) {
    return __builtin_amdgcn_mfma_f32_16x16x32_bf16(a, b, c, 0, 0, 0);
}

// ---------------------------------------------------------------------------
// Kernel 1: e1 = bf16(x@W1^T + b1), e2 = bf16(x@W2^T + b2),
//           xT[bc][f][n] = bf16(x[bc][n][f])   (per-head transpose)
// grid 1024 (= 32 heads * 32 n-tiles), block 256 (4 waves * 16 rows)
// ---------------------------------------------------------------------------
__global__ __launch_bounds__(256) void prep_kernel(
    const float* __restrict__ x,
    const float* __restrict__ W1, const float* __restrict__ b1,
    const float* __restrict__ W2, const float* __restrict__ b2,
    __bf16* __restrict__ e1, __bf16* __restrict__ e2, __bf16* __restrict__ xT)
{
    __shared__ float xs[64][68];               // fp32 stage, padded (+4)
    const int t   = threadIdx.x;
    const int blk = blockIdx.x;
    const int bc  = blk >> 5;
    const int nt  = blk & 31;
    const long grow = (long)bc * NN + nt * 64; // global row base (of 65536)

    // stage x strip [64 rows][64 f]
    {
        const int r = t >> 2, c0 = (t & 3) * 16;
        const float* src = x + (grow + r) * DD + c0;
        f32x4 v0 = *(const f32x4*)(src);
        f32x4 v1 = *(const f32x4*)(src + 4);
        f32x4 v2 = *(const f32x4*)(src + 8);
        f32x4 v3 = *(const f32x4*)(src + 12);
        *(f32x4*)&xs[r][c0]      = v0;
        *(f32x4*)&xs[r][c0 + 4]  = v1;
        *(f32x4*)&xs[r][c0 + 8]  = v2;
        *(f32x4*)&xs[r][c0 + 12] = v3;
    }
    __syncthreads();

    // transposed bf16 copy of x:  xT[(bc*64 + f)*2048 + n]
    {
        const int f = t >> 2, q = (t & 3) * 16;
        bf16x8 lo, hi;
        #pragma unroll
        for (int j = 0; j < 8; ++j) {
            lo[j] = (__bf16)xs[q + j][f];
            hi[j] = (__bf16)xs[q + 8 + j][f];
        }
        __bf16* dst = xT + ((long)bc * DD + f) * NN + nt * 64 + q;
        *(bf16x8*)(dst)     = lo;
        *(bf16x8*)(dst + 8) = hi;
    }

    // e1/e2 via MFMA; wave w owns strip rows w*16 .. w*16+15
    const int w = t >> 6, l = t & 63, lg = l >> 4, li = l & 15;
    bf16x8 a[2];
    #pragma unroll
    for (int kk = 0; kk < 2; ++kk) {
        const float* xr = &xs[w * 16 + li][kk * 32 + lg * 8];
        #pragma unroll
        for (int j = 0; j < 8; ++j) a[kk][j] = (__bf16)xr[j];
    }
    #pragma unroll
    for (int hb = 0; hb < 4; ++hb) {
        const int h = hb * 16 + li;
        bf16x8 wf1[2], wf2[2];
        #pragma unroll
        for (int kk = 0; kk < 2; ++kk) {
            const float* wr1 = W1 + h * DD + kk * 32 + lg * 8;
            const float* wr2 = W2 + h * DD + kk * 32 + lg * 8;
            #pragma unroll
            for (int j = 0; j < 8; ++j) {
                wf1[kk][j] = (__bf16)wr1[j];
                wf2[kk][j] = (__bf16)wr2[j];
            }
        }
        f32x4 acc1 = {0.f, 0.f, 0.f, 0.f};
        f32x4 acc2 = {0.f, 0.f, 0.f, 0.f};
        #pragma unroll
        for (int kk = 0; kk < 2; ++kk) {
            acc1 = mfma_bf16(a[kk], wf1[kk], acc1);
            acc2 = mfma_bf16(a[kk], wf2[kk], acc2);
        }
        const float bv1 = b1[h], bv2 = b2[h];
        #pragma unroll
        for (int r = 0; r < 4; ++r) {
            const long row = grow + w * 16 + lg * 4 + r;
            e1[row * DD + h] = (__bf16)(acc1[r] + bv1);
            e2[row * DD + h] = (__bf16)(acc2[r] + bv2);
        }
    }
}

// ---------------------------------------------------------------------------
// Kernel 2: fused  out = relu(e1 e2^T) x W3^T + b3   (flash-style, no softmax)
// grid (32 n-tiles, 32 heads), block 256 = 4 waves; BM=64 (16 rows/wave), BK=64
// ---------------------------------------------------------------------------
__global__ __launch_bounds__(256) void fused_kernel(
    const __bf16* __restrict__ e1, const __bf16* __restrict__ e2,
    const __bf16* __restrict__ xT, const float* __restrict__ W3,
    const float* __restrict__ b3, float* __restrict__ out)
{
    __shared__ __bf16 e2t[64][72];   // K-tile of e2 (rows m, cols h), 16B-aligned rows
    __shared__ __bf16 xTt[64][72];   // K-tile of x^T (rows f, cols m)
    __shared__ __bf16 Pt [64][72];   // relu(S) bf16; wave-private 16-row regions

    const int t  = threadIdx.x;
    const int nt = blockIdx.x;       // q-tile
    const int bc = blockIdx.y;       // head
    const int w = t >> 6, l = t & 63, lg = l >> 4, li = l & 15;

    // e1 A-fragments, resident across the whole K loop
    bf16x8 a1[2];
    {
        const __bf16* p = e1 + ((long)bc * NN + nt * 64 + w * 16 + li) * DD;
        a1[0] = *(const bf16x8*)(p + 0 * 32 + lg * 8);
        a1[1] = *(const bf16x8*)(p + 1 * 32 + lg * 8);
    }

    f32x4 hacc[4];
    #pragma unroll
    for (int fb = 0; fb < 4; ++fb) hacc[fb] = (f32x4){0.f, 0.f, 0.f, 0.f};

    const int lr = t >> 2, lc = (t & 3) * 16;     // cooperative-load coords
    const __bf16* e2base = e2 + (long)bc * NN * DD;
    const __bf16* xTbase = xT + (long)bc * DD * NN;

    for (int kt = 0; kt < 32; ++kt) {
        __syncthreads();             // previous tile fully consumed
        {
            const __bf16* s = e2base + (long)(kt * 64 + lr) * DD + lc;
            i32x4 u0 = *(const i32x4*)s, u1 = *(const i32x4*)(s + 8);
            *(i32x4*)&e2t[lr][lc]     = u0;
            *(i32x4*)&e2t[lr][lc + 8] = u1;
            const __bf16* s2 = xTbase + (long)lr * NN + kt * 64 + lc;
            i32x4 v0 = *(const i32x4*)s2, v1 = *(const i32x4*)(s2 + 8);
            *(i32x4*)&xTt[lr][lc]     = v0;
            *(i32x4*)&xTt[lr][lc + 8] = v1;
        }
        __syncthreads();

        // S = e1 @ e2^T  (16x64 per wave), relu -> bf16 -> Pt (wave-private rows)
        #pragma unroll
        for (int mb = 0; mb < 4; ++mb) {
            f32x4 s = {0.f, 0.f, 0.f, 0.f};
            #pragma unroll
            for (int kk = 0; kk < 2; ++kk) {
                bf16x8 bf = *(const bf16x8*)&e2t[mb * 16 + li][kk * 32 + lg * 8];
                s = mfma_bf16(a1[kk], bf, s);
            }
            #pragma unroll
            for (int r = 0; r < 4; ++r) {
                float v = s[r] > 0.f ? s[r] : 0.f;
                Pt[w * 16 + lg * 4 + r][mb * 16 + li] = (__bf16)v;
            }
        }

        // h += P @ x   (A = Pt rows, B = xTt rows; same-wave LDS dep -> lgkmcnt)
        #pragma unroll
        for (int kk2 = 0; kk2 < 2; ++kk2) {
            bf16x8 pf = *(const bf16x8*)&Pt[w * 16 + li][kk2 * 32 + lg * 8];
            #pragma unroll
            for (int fb = 0; fb < 4; ++fb) {
                bf16x8 xf = *(const bf16x8*)&xTt[fb * 16 + li][kk2 * 32 + lg * 8];
                hacc[fb] = mfma_bf16(pf, xf, hacc[fb]);
            }
        }
    }

    // epilogue: out = h @ W3^T + b3  (h round-trips through wave-private Pt rows)
    #pragma unroll
    for (int fb = 0; fb < 4; ++fb)
        #pragma unroll
        for (int r = 0; r < 4; ++r)
            Pt[w * 16 + lg * 4 + r][fb * 16 + li] = (__bf16)hacc[fb][r];

    bf16x8 hf[2];
    #pragma unroll
    for (int kk = 0; kk < 2; ++kk)
        hf[kk] = *(const bf16x8*)&Pt[w * 16 + li][kk * 32 + lg * 8];

    const long obase = ((long)bc * NN + nt * 64 + w * 16) * DD;
    #pragma unroll
    for (int ob = 0; ob < 4; ++ob) {
        bf16x8 wf[2];
        #pragma unroll
        for (int kk = 0; kk < 2; ++kk) {
            const float* wr = W3 + (ob * 16 + li) * DD + kk * 32 + lg * 8;
            #pragma unroll
            for (int j = 0; j < 8; ++j) wf[kk][j] = (__bf16)wr[j];
        }
        f32x4 acc = {0.f, 0.f, 0.f, 0.f};
        acc = mfma_bf16(hf[0], wf[0], acc);
        acc = mfma_bf16(hf[1], wf[1], acc);
        const float bv = b3[ob * 16 + li];
        #pragma unroll
        for (int r = 0; r < 4; ++r)
            out[obase + (long)(lg * 4 + r) * DD + ob * 16 + li] = acc[r] + bv;
    }
}

extern "C" void kernel_launch(void* const* d_in, const int* in_sizes, int n_in,
                              void* d_out, int out_size, void* d_ws, size_t ws_size,
                              hipStream_t stream) {
    const float* x  = (const float*)d_in[0];
    const float* W1 = (const float*)d_in[1];
    const float* b1 = (const float*)d_in[2];
    const float* W2 = (const float*)d_in[3];
    const float* b2 = (const float*)d_in[4];
    const float* W3 = (const float*)d_in[5];
    const float* b3 = (const float*)d_in[6];
    float* out = (float*)d_out;

    __bf16* e1 = (__bf16*)d_ws;                       // 32*2048*64 bf16 = 8 MB
    __bf16* e2 = e1 + (size_t)BCH * NN * DD;          // 8 MB
    __bf16* xT = e2 + (size_t)BCH * NN * DD;          // 8 MB (per-head transposed x)

    prep_kernel<<<dim3(1024), dim3(256), 0, stream>>>(x, W1, b1, W2, b2, e1, e2, xT);
    fused_kernel<<<dim3(32, 32), dim3(256), 0, stream>>>(e1, e2, xT, W3, b3, out);
}

// Round 4
// 83.915 us; speedup vs baseline: 1.1919x; 1.1919x over previous
//
#include <hip/hip_runtime.h>
#include <hip/hip_bf16.h>

#define BCH 32   // B*C heads
#define NN  2048
#define DD  64   // F = H = O

typedef __attribute__((ext_vector_type(8)))  __bf16 bf16x8;
typedef __attribute__((ext_vector_type(4)))  __bf16 bf16x4;
typedef __attribute__((ext_vector_type(4)))  float  f32x4;
typedef __attribute__((ext_vector_type(16))) float  f32x16;

__device__ inline f32x4 mfma16(bf16x8 a, bf16x8 b, f32x4 c) {
    return __builtin_amdgcn_mfma_f32_16x16x32_bf16(a, b, c, 0, 0, 0);
}
__device__ inline f32x16 mfma32(bf16x8 a, bf16x8 b, f32x16 c) {
    return __builtin_amdgcn_mfma_f32_32x32x16_bf16(a, b, c, 0, 0, 0);
}
__device__ inline void gload16(const void* g, void* l) {
    __builtin_amdgcn_global_load_lds(
        (const __attribute__((address_space(1))) void*)g,
        (__attribute__((address_space(3))) void*)l, 16, 0, 0);
}

// ---------------------------------------------------------------------------
// Kernel 1: e1 = bf16(x@W1^T + b1), e2 = bf16(x@W2^T + b2)  [bc][n][h] row-major
//           vT = bf16(x@W3^T)^T                              [bc][o][n]
// grid 1024 (32 heads * 32 strips of 64 rows), block 256 (4 waves * 16 rows)
// ---------------------------------------------------------------------------
__global__ __launch_bounds__(256) void prep_kernel(
    const float* __restrict__ x,
    const float* __restrict__ W1, const float* __restrict__ b1,
    const float* __restrict__ W2, const float* __restrict__ b2,
    const float* __restrict__ W3,
    __bf16* __restrict__ e1, __bf16* __restrict__ e2, __bf16* __restrict__ vT)
{
    const int t   = threadIdx.x;
    const int blk = blockIdx.x;
    const int bc  = blk >> 5, nt = blk & 31;
    const long grow = (long)bc * NN + nt * 64;
    const int w = t >> 6, l = t & 63, lg = l >> 4, li = l & 15;

    // A-fragments of x (rows w*16+li), fp32 -> bf16
    bf16x8 a[2];
    #pragma unroll
    for (int kk = 0; kk < 2; ++kk) {
        const float* xr = x + (grow + w * 16 + li) * DD + kk * 32 + lg * 8;
        f32x4 v0 = *(const f32x4*)xr, v1 = *(const f32x4*)(xr + 4);
        #pragma unroll
        for (int j = 0; j < 4; ++j) { a[kk][j] = (__bf16)v0[j]; a[kk][4 + j] = (__bf16)v1[j]; }
    }

    #pragma unroll
    for (int hb = 0; hb < 4; ++hb) {
        const int h = hb * 16 + li;
        bf16x8 wf1[2], wf2[2], wf3[2];
        #pragma unroll
        for (int kk = 0; kk < 2; ++kk) {
            const float* p1 = W1 + h * DD + kk * 32 + lg * 8;
            const float* p2 = W2 + h * DD + kk * 32 + lg * 8;
            const float* p3 = W3 + h * DD + kk * 32 + lg * 8;
            #pragma unroll
            for (int j = 0; j < 8; ++j) {
                wf1[kk][j] = (__bf16)p1[j];
                wf2[kk][j] = (__bf16)p2[j];
                wf3[kk][j] = (__bf16)p3[j];
            }
        }
        f32x4 acc1 = {0.f,0.f,0.f,0.f}, acc2 = {0.f,0.f,0.f,0.f}, acc3 = {0.f,0.f,0.f,0.f};
        #pragma unroll
        for (int kk = 0; kk < 2; ++kk) {
            acc1 = mfma16(a[kk], wf1[kk], acc1);
            acc2 = mfma16(a[kk], wf2[kk], acc2);
            acc3 = mfma16(a[kk], wf3[kk], acc3);
        }
        const float bv1 = b1[h], bv2 = b2[h];
        #pragma unroll
        for (int r = 0; r < 4; ++r) {
            const long row = grow + w * 16 + lg * 4 + r;
            e1[row * DD + h] = (__bf16)(acc1[r] + bv1);
            e2[row * DD + h] = (__bf16)(acc2[r] + bv2);
        }
        // vT[o][n]: 4 consecutive n per lane -> packed 8B store (no bias)
        bf16x4 p4;
        #pragma unroll
        for (int r = 0; r < 4; ++r) p4[r] = (__bf16)acc3[r];
        *(bf16x4*)&vT[((long)bc * DD + h) * NN + nt * 64 + w * 16 + lg * 4] = p4;
    }
}

// ---------------------------------------------------------------------------
// Kernel 2: out = relu(e1 e2^T) v + b3, flash-style.
// grid (16 q-tiles, 32 heads), block 256 = 4 waves; BM=128 (32 rows/wave), BK=64.
// 32x32x16 MFMA. LDS tiles [64][64] bf16, XOR-swizzled 16B slots, staged via
// global_load_lds (pre-swizzled global source). Pt wave-private (S^T trick:
// 4 consecutive m per reg-quad -> b64 packed writes).
// ---------------------------------------------------------------------------
__global__ __launch_bounds__(256) void fused_kernel(
    const __bf16* __restrict__ e1, const __bf16* __restrict__ e2,
    const __bf16* __restrict__ vT, const float* __restrict__ b3,
    float* __restrict__ out)
{
    __shared__ __bf16 e2t[2][64 * 64];   // [m][h], swizzled
    __shared__ __bf16 vTt[2][64 * 64];   // [o][m], swizzled
    __shared__ __bf16 Pt [4][32 * 64];   // per-wave [n][m], swizzled

    const int t  = threadIdx.x;
    const int nt = blockIdx.x;           // 0..15
    const int bc = blockIdx.y;           // 0..31
    const int w = t >> 6, l = t & 63;
    const int l31 = l & 31, hi5 = l >> 5, l7 = l & 7, l3 = l >> 3;

    // resident e1 B-fragments: row n = nt*128 + w*32 + l31, k = kk*16 + hi5*8
    bf16x8 e1f[4];
    {
        const __bf16* p = e1 + ((size_t)bc * NN + nt * 128 + w * 32 + l31) * DD;
        #pragma unroll
        for (int kk = 0; kk < 4; ++kk) e1f[kk] = *(const bf16x8*)(p + kk * 16 + hi5 * 8);
    }

    f32x16 hacc[2];
    #pragma unroll
    for (int i = 0; i < 16; ++i) { hacc[0][i] = 0.f; hacc[1][i] = 0.f; }

    const __bf16* e2h = e2 + (size_t)bc * NN * DD;
    const __bf16* vTh = vT + (size_t)bc * DD * NN;

    // stage K-tile kt into buffer buf: 8 chunks of 1KB each per array,
    // wave w issues chunks 2w, 2w+1. Lane l -> row = ch*8+l3, phys slot l&7,
    // global slot q = l7 ^ l3 (so LDS slot s holds global slot s^(row&7)).
    auto stage = [&](int buf, int kt) {
        #pragma unroll
        for (int ii = 0; ii < 2; ++ii) {
            const int ch  = w * 2 + ii;
            const int row = ch * 8 + l3;
            const int q   = l7 ^ l3;
            gload16(e2h + ((size_t)(kt * 64 + row)) * DD + q * 8, &e2t[buf][ch * 512]);
            gload16(vTh + ((size_t)row) * NN + kt * 64 + q * 8, &vTt[buf][ch * 512]);
        }
    };

    stage(0, 0);
    __syncthreads();

    for (int kt = 0; kt < 32; ++kt) {
        const int buf = kt & 1;
        if (kt + 1 < 32) stage(buf ^ 1, kt + 1);

        // S^T = e2 @ e1^T : D[m][n], per mb block of 32 m
        #pragma unroll
        for (int mb = 0; mb < 2; ++mb) {
            f32x16 s;
            #pragma unroll
            for (int i = 0; i < 16; ++i) s[i] = 0.f;
            #pragma unroll
            for (int kk = 0; kk < 4; ++kk) {
                const int slot = (kk * 2 + hi5) ^ l7;           // row&7 == l7
                bf16x8 ef = *(const bf16x8*)&e2t[buf][(mb * 32 + l31) * 64 + slot * 8];
                s = mfma32(ef, e1f[kk], s);
            }
            // relu + pack 4 consecutive m (reg quad) -> b64 write to Pt[n][m]
            #pragma unroll
            for (int g = 0; g < 4; ++g) {
                bf16x4 p4;
                #pragma unroll
                for (int r = 0; r < 4; ++r) {
                    float v = s[4 * g + r];
                    p4[r] = (__bf16)(v > 0.f ? v : 0.f);
                }
                const int slot = (mb * 4 + g) ^ l7;             // n&7 == l7
                *(bf16x4*)&Pt[w][l31 * 64 + slot * 8 + hi5 * 4] = p4;
            }
        }

        // PV: hacc[n][f] += P[n][m] * vT[f][m]
        #pragma unroll
        for (int kk2 = 0; kk2 < 4; ++kk2) {
            const int slot = (kk2 * 2 + hi5) ^ l7;
            bf16x8 pf = *(const bf16x8*)&Pt[w][l31 * 64 + slot * 8];
            #pragma unroll
            for (int fb = 0; fb < 2; ++fb) {
                bf16x8 vf = *(const bf16x8*)&vTt[buf][(fb * 32 + l31) * 64 + slot * 8];
                hacc[fb] = mfma32(pf, vf, hacc[fb]);
            }
        }

        __syncthreads();   // drains staging vmcnt; all reads of buf done
    }

    // epilogue: out = hacc + b3 (fp32). C-layout: col f = fb*32+l31,
    // row n = (reg&3) + 8*(reg>>2) + 4*hi5
    const float bv0 = b3[l31], bv1 = b3[32 + l31];
    const size_t obase = ((size_t)bc * NN + nt * 128 + w * 32) * DD;
    #pragma unroll
    for (int reg = 0; reg < 16; ++reg) {
        const int n = (reg & 3) + 8 * (reg >> 2) + 4 * hi5;
        out[obase + (size_t)n * DD + l31]      = hacc[0][reg] + bv0;
        out[obase + (size_t)n * DD + 32 + l31] = hacc[1][reg] + bv1;
    }
}

extern "C" void kernel_launch(void* const* d_in, const int* in_sizes, int n_in,
                              void* d_out, int out_size, void* d_ws, size_t ws_size,
                              hipStream_t stream) {
    const float* x  = (const float*)d_in[0];
    const float* W1 = (const float*)d_in[1];
    const float* b1 = (const float*)d_in[2];
    const float* W2 = (const float*)d_in[3];
    const float* b2 = (const float*)d_in[4];
    const float* W3 = (const float*)d_in[5];
    const float* b3 = (const float*)d_in[6];
    float* out = (float*)d_out;

    __bf16* e1 = (__bf16*)d_ws;                       // 8 MB
    __bf16* e2 = e1 + (size_t)BCH * NN * DD;          // 8 MB
    __bf16* vT = e2 + (size_t)BCH * NN * DD;          // 8 MB

    prep_kernel<<<dim3(1024), dim3(256), 0, stream>>>(x, W1, b1, W2, b2, W3, e1, e2, vT);
    fused_kernel<<<dim3(16, 32), dim3(256), 0, stream>>>(e1, e2, vT, b3, out);
}